// Round 19
// baseline (49.218 us; speedup 1.0000x reference)
//
#include <hip/hip_runtime.h>
#include <hip/hip_bf16.h>

#define HH 56
#define WW 56
#define CIN 64
#define COUT 64
#define BATCH 32
#define KK 9
#define HWP (HH*WW)          // 3136
#define NS 18                // K-steps of 32 (576/32)
#define NTILE 49
#define NBLK (NTILE*BATCH)   // 1568 = 8 * 196

typedef __attribute__((ext_vector_type(8))) short short8;
typedef __attribute__((ext_vector_type(4))) float float4v;
typedef __attribute__((ext_vector_type(4))) unsigned int uint4v;

// bf16 RNE (reference-matching); kept for the weight prepack path
__device__ __forceinline__ unsigned short f2bf(float f) {
    union { float f; unsigned u; } v; v.f = f;
    unsigned r = v.u + 0x7FFFu + ((v.u >> 16) & 1u);
    return (unsigned short)(r >> 16);
}

// pack two f32 -> one u32 of 2 bf16 (RNE), ch-even in low half
__device__ __forceinline__ unsigned pk2bf(float a, float b) {
    __hip_bfloat162 h = __float22bfloat162_rn(make_float2(a, b));
    union { __hip_bfloat162 h; unsigned u; } v; v.h = h;
    return v.u;
}

// 16x16x32 A-fragment prepack: o = mb*16 + (l&15); c = (s&1)*32 + (l>>4)*8 + j
__global__ __launch_bounds__(256) void prep_weights(
    const float* __restrict__ w, unsigned short* __restrict__ apack)
{
    int e = blockIdx.x * 256 + threadIdx.x;      // 0..36863
    int j = e & 7;
    int l = (e >> 3) & 63;
    int ss = e >> 9;
    int mb = ss / 18;
    int s  = ss - mb * 18;
    int o = mb * 16 + (l & 15);
    int c = ((s & 1) << 5) + ((l >> 4) << 3) + j;
    int k = s >> 1;
    apack[e] = f2bf(w[(o * CIN + c) * KK + k]);
}

// ---- main: R13 compute structure, staging fused (x f32 -> bf16 LDS in-kernel) ----
__global__ __launch_bounds__(256) void dconv_main(
    const float* __restrict__ x, const int* __restrict__ sidx,
    const unsigned short* __restrict__ apack, float* __restrict__ out)
{
    // xs[row][quad]: 496 rows x 64 B (16 c2 per phase), quad swizzled by row&3
    __shared__ unsigned int xs[496 * 16];        // 31,744 B

    const int t    = threadIdx.x;
    const int lane = t & 63;
    const int wv   = t >> 6;
    const int mbp  = wv >> 1;
    const int ntp  = wv & 1;
    const int col  = lane & 15;
    const int krow = lane >> 4;

    // XCD-aware bijective swizzle: 1568 = 8*196 -> 4 consecutive batches/XCD
    int bid  = blockIdx.x;
    int orig = (bid & 7) * 196 + (bid >> 3);
    int b    = orig / NTILE;
    int bx   = orig - b * NTILE;
    int ti = bx / 7, tj = bx - (bx / 7) * 7;
    int r0 = ti * 8 - 7; if (r0 < 0) r0 = 0;
    int c0 = tj * 8 - 7; if (c0 < 0) c0 = 0;

    // ---- staging source pixels (computed once, reused by both phases) ----
    const int cg = t & 3;                        // channel group (8 ch)
    const int ps = t >> 2;                       // pixel slot 0..63
    int gsrc[8];
    #pragma unroll
    for (int pass = 0; pass < 8; ++pass) {
        int s  = ps + pass * 64;
        int sc = s < 483 ? s : 483;
        int lsr = sc / 22, lsc = sc - lsr * 22;
        int si = r0 + lsr; if (si > HH - 1) si = HH - 1;
        int sj = c0 + lsc; if (sj > WW - 1) sj = WW - 1;
        gsrc[pass] = si * WW + sj;
    }

    // ---- per-lane gather byte offsets (row*64 + swizzled quad) ----
    int lb[2][KK];
    #pragma unroll
    for (int nn = 0; nn < 2; ++nn) {
        int p  = (ntp * 2 + nn) * 16 + col;
        int gi = ti * 8 + (p >> 3), gj = tj * 8 + (p & 7);
        const int* sp = sidx + (gi * WW + gj) * KK;
        #pragma unroll
        for (int k = 0; k < KK; ++k) {
            int g  = sp[k];
            int si = g / WW, sj = g - si * WW;
            int row = (si - r0) * 22 + (sj - c0);
            lb[nn][k] = row * 64 + ((krow ^ (row & 3)) << 4);
        }
    }

    const unsigned short* apW = apack + (size_t)(mbp * 2 * NS) * 512 + lane * 8;
    const float* xb = x + (size_t)b * CIN * HWP;

    float4v zero = {0.f, 0.f, 0.f, 0.f};
    float4v acc[2][2] = {{zero, zero}, {zero, zero}};
    const char* xsb = (const char*)xs;

    #pragma unroll
    for (int sh = 0; sh < 2; ++sh) {
        // ---- stage phase sh: channels [sh*32 + cg*8, +8) for my pixel slots ----
        const float* xc = xb + (size_t)(sh * 32 + cg * 8) * HWP;
        #pragma unroll
        for (int pass = 0; pass < 8; ++pass) {
            int s = ps + pass * 64;
            if (s < 484) {
                int g = gsrc[pass];
                float f0 = xc[g];
                float f1 = xc[(size_t)1 * HWP + g];
                float f2 = xc[(size_t)2 * HWP + g];
                float f3 = xc[(size_t)3 * HWP + g];
                float f4 = xc[(size_t)4 * HWP + g];
                float f5 = xc[(size_t)5 * HWP + g];
                float f6 = xc[(size_t)6 * HWP + g];
                float f7 = xc[(size_t)7 * HWP + g];
                uint4v u;
                u[0] = pk2bf(f0, f1);
                u[1] = pk2bf(f2, f3);
                u[2] = pk2bf(f4, f5);
                u[3] = pk2bf(f6, f7);
                int wq = cg ^ (s & 3);           // write-side swizzle
                *(uint4v*)(xs + s * 16 + wq * 4) = u;   // one ds_write_b128
            }
        }
        __syncthreads();   // LDS ready

        // ---- compute phase sh: K-steps s = 2k+sh (identical to R13) ----
        #pragma unroll
        for (int k = 0; k < KK; ++k) {
            short8 a0 = *(const short8*)(apW + (size_t)(2 * k + sh) * 512);
            short8 a1 = *(const short8*)(apW + (size_t)(NS + 2 * k + sh) * 512);
            #pragma unroll
            for (int nn = 0; nn < 2; ++nn) {
                short8 bv = *(const short8*)(xsb + lb[nn][k]);
                acc[0][nn] = __builtin_amdgcn_mfma_f32_16x16x32_bf16(
                    a0, bv, acc[0][nn], 0, 0, 0);
                acc[1][nn] = __builtin_amdgcn_mfma_f32_16x16x32_bf16(
                    a1, bv, acc[1][nn], 0, 0, 0);
            }
        }
        if (sh == 0) __syncthreads();   // protect buffer before phase-1 restage
    }

    // ---- epilogue ----
    float* ob = out + ((size_t)b * COUT + mbp * 32) * HWP;
    #pragma unroll
    for (int m = 0; m < 2; ++m) {
        #pragma unroll
        for (int nn = 0; nn < 2; ++nn) {
            int p = (ntp * 2 + nn) * 16 + col;
            int g = (ti * 8 + (p >> 3)) * WW + tj * 8 + (p & 7);
            #pragma unroll
            for (int r = 0; r < 4; ++r)
                ob[(m * 16 + krow * 4 + r) * HWP + g] = acc[m][nn][r];
        }
    }
}

extern "C" void kernel_launch(void* const* d_in, const int* in_sizes, int n_in,
                              void* d_out, int out_size, void* d_ws, size_t ws_size,
                              hipStream_t stream) {
    const float* x    = (const float*)d_in[0];
    const float* w    = (const float*)d_in[1];
    const int*   sidx = (const int*)d_in[2];
    float* out = (float*)d_out;
    unsigned short* apack = (unsigned short*)d_ws;   // 72 KiB

    prep_weights<<<144, 256, 0, stream>>>(w, apack);
    dconv_main<<<NBLK, 256, 0, stream>>>(x, sidx, apack, out);
}

// Round 20
// 32.430 us; speedup vs baseline: 1.5177x; 1.5177x over previous
//
#include <hip/hip_runtime.h>
#include <hip/hip_bf16.h>

#define HH 56
#define WW 56
#define CIN 64
#define COUT 64
#define BATCH 32
#define KK 9
#define HWP (HH*WW)          // 3136
#define NS 18                // K-steps of 32 (576/32)
#define NTILE 49
#define NBLK (NTILE*BATCH)   // 1568 = 8 * 196
#define XT_OFF 73728         // apack (72 KiB) precedes xt in d_ws
#define XSW 33               // fallback LDS stride

typedef __attribute__((ext_vector_type(8))) short short8;
typedef __attribute__((ext_vector_type(4))) float float4v;
typedef __attribute__((ext_vector_type(4))) unsigned int uint4v;

__device__ __forceinline__ unsigned short f2bf(float f) {
    union { float f; unsigned u; } v; v.f = f;
    unsigned r = v.u + 0x7FFFu + ((v.u >> 16) & 1u);
    return (unsigned short)(r >> 16);
}

// 16x16x32 A-fragment prepack: o = mb*16 + (l&15); c = (s&1)*32 + (l>>4)*8 + j
__device__ __forceinline__ void prepack_elem(const float* __restrict__ w,
                                             unsigned short* __restrict__ apack,
                                             int e) {
    int j = e & 7;
    int l = (e >> 3) & 63;
    int ss = e >> 9;
    int mb = ss / 18;
    int s  = ss - mb * 18;
    int o = mb * 16 + (l & 15);
    int c = ((s & 1) << 5) + ((l >> 4) << 3) + j;
    int k = s >> 1;
    apack[e] = f2bf(w[(o * CIN + c) * KK + k]);
}

// Merged prep: blocks [0,784) transpose x (float4-vectorized) -> xt[b][hw][c2];
//              blocks [784,928) prepack weights (16x16 layout).
__global__ __launch_bounds__(256) void prep_kernel(
    const float* __restrict__ x, const float* __restrict__ w,
    unsigned int* __restrict__ xt, unsigned short* __restrict__ apack)
{
    int bid = blockIdx.x;
    int t   = threadIdx.x;
    if (bid < 784) {
        int u   = bid * 256 + t;          // 0..200703
        int c2q = u & 7;
        int hq  = u >> 3;                 // b*784 + q
        int b   = hq / 784;
        int q   = hq - b * 784;
        int hw  = q * 4;
        const float* xb = x + ((size_t)b * CIN + c2q * 8) * HWP + hw;
        float4v f[8];
        #pragma unroll
        for (int i = 0; i < 8; ++i)
            f[i] = *(const float4v*)(xb + (size_t)i * HWP);
        unsigned int* xto = xt + ((size_t)b * HWP + hw) * 32 + c2q * 4;
        #pragma unroll
        for (int j = 0; j < 4; ++j) {
            uint4v o;
            #pragma unroll
            for (int ci = 0; ci < 4; ++ci)
                o[ci] = (unsigned)f2bf(f[2 * ci][j]) |
                        ((unsigned)f2bf(f[2 * ci + 1][j]) << 16);
            *(uint4v*)(xto + (size_t)j * 32) = o;
        }
    } else {
        prepack_elem(w, apack, (bid - 784) * 256 + t);
    }
}

__global__ __launch_bounds__(256) void prep_weights_only(
    const float* __restrict__ w, unsigned short* __restrict__ apack)
{
    prepack_elem(w, apack, blockIdx.x * 256 + threadIdx.x);
}

// ------- main: R13 (2-phase K-split, 31 KB LDS, A loaded per-k from L2) -------
__global__ __launch_bounds__(256) void dconv_main(
    const unsigned int* __restrict__ xt, const int* __restrict__ sidx,
    const unsigned short* __restrict__ apack, float* __restrict__ out)
{
    // xs[row][quad]: 496 rows x 64 B (16 c2 per phase), quad swizzled by row&3
    __shared__ unsigned int xs[496 * 16];        // 31,744 B

    const int t    = threadIdx.x;
    const int lane = t & 63;
    const int wv   = t >> 6;
    const int mbp  = wv >> 1;
    const int ntp  = wv & 1;
    const int col  = lane & 15;
    const int krow = lane >> 4;

    // XCD-aware bijective swizzle: 1568 = 8*196 -> 4 consecutive batches/XCD
    int bid  = blockIdx.x;
    int orig = (bid & 7) * 196 + (bid >> 3);
    int b    = orig / NTILE;
    int bx   = orig - b * NTILE;
    int ti = bx / 7, tj = bx - (bx / 7) * 7;
    int r0 = ti * 8 - 7; if (r0 < 0) r0 = 0;
    int c0 = tj * 8 - 7; if (c0 < 0) c0 = 0;

    const unsigned int* xtb = xt + (size_t)b * HWP * 32;

    // ---- per-lane gather byte offsets (row*64 + swizzled quad) ----
    int lb[2][KK];
    #pragma unroll
    for (int nn = 0; nn < 2; ++nn) {
        int p  = (ntp * 2 + nn) * 16 + col;
        int gi = ti * 8 + (p >> 3), gj = tj * 8 + (p & 7);
        const int* sp = sidx + (gi * WW + gj) * KK;
        #pragma unroll
        for (int k = 0; k < KK; ++k) {
            int g  = sp[k];
            int si = g / WW, sj = g - si * WW;
            int row = (si - r0) * 22 + (sj - c0);
            lb[nn][k] = row * 64 + ((krow ^ (row & 3)) << 4);
        }
    }

    const unsigned short* apW = apack + (size_t)(mbp * 2 * NS) * 512 + lane * 8;

    float4v zero = {0.f, 0.f, 0.f, 0.f};
    float4v acc[2][2] = {{zero, zero}, {zero, zero}};
    const char* xsb = (const char*)xs;

    #pragma unroll
    for (int sh = 0; sh < 2; ++sh) {
        // ---- stage phase sh: 16 c2-rows (64 B) per pixel row ----
        for (int grp = wv; grp < 31; grp += 4) {
            int row = grp * 16 + (lane >> 2);
            int rc  = row < 483 ? row : 483;     // clamp pad slots
            int lsr = rc / 22;
            int lsc = rc - lsr * 22;
            int si = r0 + lsr; if (si > HH - 1) si = HH - 1;
            int sj = c0 + lsc; if (sj > WW - 1) sj = WW - 1;
            int q  = (lane & 3) ^ (rc & 3);      // source-side swizzle
            const unsigned int* src =
                xtb + (size_t)(si * WW + sj) * 32 + sh * 16 + (q << 2);
            __builtin_amdgcn_global_load_lds(
                (const __attribute__((address_space(1))) unsigned int*)src,
                (__attribute__((address_space(3))) unsigned int*)(xs + grp * 256),
                16, 0, 0);
        }
        __syncthreads();   // drains vmcnt -> LDS ready

        // ---- compute phase sh: K-steps s = 2k+sh ----
        #pragma unroll
        for (int k = 0; k < KK; ++k) {
            short8 a0 = *(const short8*)(apW + (size_t)(2 * k + sh) * 512);
            short8 a1 = *(const short8*)(apW + (size_t)(NS + 2 * k + sh) * 512);
            #pragma unroll
            for (int nn = 0; nn < 2; ++nn) {
                short8 bv = *(const short8*)(xsb + lb[nn][k]);
                acc[0][nn] = __builtin_amdgcn_mfma_f32_16x16x32_bf16(
                    a0, bv, acc[0][nn], 0, 0, 0);
                acc[1][nn] = __builtin_amdgcn_mfma_f32_16x16x32_bf16(
                    a1, bv, acc[1][nn], 0, 0, 0);
            }
        }
        if (sh == 0) __syncthreads();   // protect buffer before phase-1 restage
    }

    // ---- epilogue ----
    float* ob = out + ((size_t)b * COUT + mbp * 32) * HWP;
    #pragma unroll
    for (int m = 0; m < 2; ++m) {
        #pragma unroll
        for (int nn = 0; nn < 2; ++nn) {
            int p = (ntp * 2 + nn) * 16 + col;
            int g = (ti * 8 + (p >> 3)) * WW + tj * 8 + (p & 7);
            #pragma unroll
            for (int r = 0; r < 4; ++r)
                ob[(m * 16 + krow * 4 + r) * HWP + g] = acc[m][nn][r];
        }
    }
}

// ---------------- fallback (round-5 path, if ws too small) ----------------
__global__ __launch_bounds__(256, 2) void dconv_fb(
    const float* __restrict__ x, const int* __restrict__ sidx,
    const unsigned short* __restrict__ apack, float* __restrict__ out)
{
    __shared__ unsigned int xs[484 * XSW];

    const int t    = threadIdx.x;
    const int lane = t & 63;
    const int wv   = t >> 6;
    const int mbp  = wv >> 1;
    const int ntp  = wv & 1;
    const int col  = lane & 15;
    const int krow = lane >> 4;
    const int bx   = blockIdx.x;
    const int b    = blockIdx.y;
    const int ti = bx / 7, tj = bx - (bx / 7) * 7;
    int r0 = ti * 8 - 7; if (r0 < 0) r0 = 0;
    int r1 = ti * 8 + 14; if (r1 > HH - 1) r1 = HH - 1;
    int c0 = tj * 8 - 7; if (c0 < 0) c0 = 0;
    int c1 = tj * 8 + 14; if (c1 > WW - 1) c1 = WW - 1;

    int lb[2][KK];
    #pragma unroll
    for (int nn = 0; nn < 2; ++nn) {
        int p  = (ntp * 2 + nn) * 16 + col;
        int gi = ti * 8 + (p >> 3), gj = tj * 8 + (p & 7);
        const int* sp = sidx + (gi * WW + gj) * KK;
        #pragma unroll
        for (int k = 0; k < KK; ++k) {
            int g  = sp[k];
            int si = g / WW, sj = g - si * WW;
            lb[nn][k] = ((si - r0) * 22 + (sj - c0)) * (XSW * 4);
        }
    }

    short8 areg[2][NS];
    #pragma unroll
    for (int m = 0; m < 2; ++m) {
        const unsigned short* ap = apack + ((mbp * 2 + m) * NS) * 512 + lane * 8;
        #pragma unroll
        for (int s = 0; s < NS; ++s)
            areg[m][s] = *(const short8*)(ap + s * 512);
    }

    const float* xb = x + (size_t)b * CIN * HWP;
    for (int e = t; e < 32 * 512; e += 256) {
        int c2 = e >> 9, ls = e & 511;
        if (ls < 484) {
            int lsr = ls / 22;
            int si = r0 + lsr, sj = c0 + (ls - lsr * 22);
            if (si <= r1 && sj <= c1) {
                int g = si * WW + sj;
                float f0 = xb[(2 * c2) * HWP + g];
                float f1 = xb[(2 * c2 + 1) * HWP + g];
                xs[ls * XSW + c2] =
                    (unsigned)f2bf(f0) | ((unsigned)f2bf(f1) << 16);
            }
        }
    }
    __syncthreads();

    float4v zero = {0.f, 0.f, 0.f, 0.f};
    float4v acc[2][2] = {{zero, zero}, {zero, zero}};
    const char* xsb = (const char*)xs + krow * 16;

    #pragma unroll
    for (int k = 0; k < KK; ++k) {
        #pragma unroll
        for (int nn = 0; nn < 2; ++nn) {
            const char* ba = xsb + lb[nn][k];
            union { int i[4]; short8 s8; } b0, b1;
            #pragma unroll
            for (int w = 0; w < 4; ++w) {
                b0.i[w] = *(const int*)(ba + w * 4);
                b1.i[w] = *(const int*)(ba + 64 + w * 4);
            }
            acc[0][nn] = __builtin_amdgcn_mfma_f32_16x16x32_bf16(
                areg[0][2 * k], b0.s8, acc[0][nn], 0, 0, 0);
            acc[1][nn] = __builtin_amdgcn_mfma_f32_16x16x32_bf16(
                areg[1][2 * k], b0.s8, acc[1][nn], 0, 0, 0);
            acc[0][nn] = __builtin_amdgcn_mfma_f32_16x16x32_bf16(
                areg[0][2 * k + 1], b1.s8, acc[0][nn], 0, 0, 0);
            acc[1][nn] = __builtin_amdgcn_mfma_f32_16x16x32_bf16(
                areg[1][2 * k + 1], b1.s8, acc[1][nn], 0, 0, 0);
        }
    }

    float* ob = out + ((size_t)b * COUT + mbp * 32) * HWP;
    #pragma unroll
    for (int m = 0; m < 2; ++m) {
        #pragma unroll
        for (int nn = 0; nn < 2; ++nn) {
            int p = (ntp * 2 + nn) * 16 + col;
            int g = (ti * 8 + (p >> 3)) * WW + tj * 8 + (p & 7);
            #pragma unroll
            for (int r = 0; r < 4; ++r)
                ob[(m * 16 + krow * 4 + r) * HWP + g] = acc[m][nn][r];
        }
    }
}

extern "C" void kernel_launch(void* const* d_in, const int* in_sizes, int n_in,
                              void* d_out, int out_size, void* d_ws, size_t ws_size,
                              hipStream_t stream) {
    const float* x    = (const float*)d_in[0];
    const float* w    = (const float*)d_in[1];
    const int*   sidx = (const int*)d_in[2];
    float* out = (float*)d_out;
    unsigned short* apack = (unsigned short*)d_ws;                  // 72 KiB
    unsigned int*   xt    = (unsigned int*)((char*)d_ws + XT_OFF);  // 12.84 MB

    size_t need = (size_t)XT_OFF + (size_t)BATCH * HWP * 128;
    if (ws_size >= need) {
        prep_kernel<<<928, 256, 0, stream>>>(x, w, xt, apack);
        dconv_main<<<NBLK, 256, 0, stream>>>(xt, sidx, apack, out);
    } else {
        prep_weights_only<<<144, 256, 0, stream>>>(w, apack);
        dim3 grid(NTILE, BATCH);
        dconv_fb<<<grid, 256, 0, stream>>>(x, sidx, apack, out);
    }
}